// Round 4
// baseline (1567.398 us; speedup 1.0000x reference)
//
#include <hip/hip_runtime.h>
#include <math.h>

#define L_ 4
#define D_ 256
#define H_ 8
#define INNER_ 2048
#define M_ 1024
#define B_ 8
#define N_ 1024
#define R_ (B_ * N_)          // 8192 rows
#define QS_ 6144              // qkv row stride (3*INNER)

constexpr float EPS_ = 1e-5f;
constexpr float SCALE_ = 0.0625f;  // 256^-0.5

using f16 = _Float16;
typedef _Float16 f16x8 __attribute__((ext_vector_type(8)));
typedef float f32x4 __attribute__((ext_vector_type(4)));

__device__ __forceinline__ float gelu_f(float x) {
    return 0.5f * x * (1.0f + erff(x * 0.70710678118654752f));
}

// ---------------------------------------------------------------------------
// LayerNorm: one block per row of 256, 256 threads; fp32 in, f16 out
// ---------------------------------------------------------------------------
__global__ __launch_bounds__(256)
void ln_kernel(const float* __restrict__ x, const float* __restrict__ g,
               const float* __restrict__ b, f16* __restrict__ out) {
    const int row = blockIdx.x;
    const int t = threadIdx.x;
    const int wave = t >> 6, lane = t & 63;
    __shared__ float red[8];

    const float v = x[(size_t)row * D_ + t];

    float s = v;
    #pragma unroll
    for (int o = 32; o; o >>= 1) s += __shfl_down(s, o);
    if (lane == 0) red[wave] = s;
    __syncthreads();
    const float mean = (red[0] + red[1] + red[2] + red[3]) * (1.0f / 256.0f);

    const float d = v - mean;
    float s2 = d * d;
    #pragma unroll
    for (int o = 32; o; o >>= 1) s2 += __shfl_down(s2, o);
    if (lane == 0) red[4 + wave] = s2;
    __syncthreads();
    const float var = (red[4] + red[5] + red[6] + red[7]) * (1.0f / 256.0f);

    out[(size_t)row * D_ + t] = (f16)(d * rsqrtf(var + EPS_) * g[t] + b[t]);
}

// ---------------------------------------------------------------------------
// Weight transpose+convert: W[K][N] f32 -> Wt[N][K] f16.  64x64 tiles,
// grid (N/64, K/64, L). K,N multiples of 64.
// ---------------------------------------------------------------------------
__global__ __launch_bounds__(256)
void transpose_w(const float* __restrict__ W, f16* __restrict__ Wt, int K, int N) {
    __shared__ float tile[64][68];
    const int n0 = blockIdx.x * 64, k0 = blockIdx.y * 64;
    const float* Wl = W + (size_t)blockIdx.z * K * N;
    f16* Wtl = Wt + (size_t)blockIdx.z * K * N;
    const int t = threadIdx.x;

    #pragma unroll
    for (int j = 0; j < 4; ++j) {
        const int li = t + 256 * j;
        const int r = li >> 4, c4 = (li & 15) * 4;
        const float4 v = *reinterpret_cast<const float4*>(&Wl[(size_t)(k0 + r) * N + n0 + c4]);
        tile[r][c4] = v.x; tile[r][c4 + 1] = v.y; tile[r][c4 + 2] = v.z; tile[r][c4 + 3] = v.w;
    }
    __syncthreads();
    #pragma unroll
    for (int j = 0; j < 2; ++j) {
        const int li = t + 256 * j;
        const int n = li >> 3, c8 = (li & 7) * 8;
        f16 tmp[8];
        #pragma unroll
        for (int e = 0; e < 8; ++e) tmp[e] = (f16)tile[c8 + e][n];
        *reinterpret_cast<uint4*>(&Wtl[(size_t)(n0 + n) * K + k0 + c8]) =
            *reinterpret_cast<const uint4*>(tmp);
    }
}

// ---------------------------------------------------------------------------
// V transpose: qkv V-slot [token][2048] -> Vt [b][2048][1024] (all f16).
// grid (N/64, 2048/64, CB)
// ---------------------------------------------------------------------------
__global__ __launch_bounds__(256)
void transpose_v(const f16* __restrict__ qkv, f16* __restrict__ Vt) {
    __shared__ f16 tile[64][72];
    const int n0 = blockIdx.x * 64;      // token
    const int d0 = blockIdx.y * 64;      // col within 2048
    const int b = blockIdx.z;
    const int t = threadIdx.x;
    const f16* Vg = qkv + (size_t)b * N_ * QS_ + 4096;

    #pragma unroll
    for (int j = 0; j < 2; ++j) {
        const int li = t + 256 * j;
        const int r = li >> 3, c8 = (li & 7) * 8;
        *reinterpret_cast<uint4*>(&tile[r][c8]) =
            *reinterpret_cast<const uint4*>(&Vg[(size_t)(n0 + r) * QS_ + d0 + c8]);
    }
    __syncthreads();
    #pragma unroll
    for (int j = 0; j < 2; ++j) {
        const int li = t + 256 * j;
        const int dr = li >> 3, c8 = (li & 7) * 8;
        f16 tmp[8];
        #pragma unroll
        for (int e = 0; e < 8; ++e) tmp[e] = tile[c8 + e][dr];
        *reinterpret_cast<uint4*>(&Vt[((size_t)b * INNER_ + d0 + dr) * N_ + n0 + c8]) =
            *reinterpret_cast<const uint4*>(tmp);
    }
}

// ---------------------------------------------------------------------------
// f16 MFMA GEMM: C[rows x Nc] = A[rows x K] @ Wt^T  (Wt is [Nc][K], k-contig)
// Block tile (2*WM x 2*WN), BK=64, 256 threads = 4 waves in 2x2.
// LDS tiles in 16B chunks, XOR-swizzled: chunk' = c ^ (row&7)  (8 chunks/row).
// ---------------------------------------------------------------------------
template <int WM, int WN, bool BIAS, bool RES, bool GELU, bool OUTF16>
__global__ __launch_bounds__(256)
void gemm_f16(const f16* __restrict__ A, int lda, const f16* __restrict__ Wt,
              const float* __restrict__ bias, f16* __restrict__ Cf16,
              float* __restrict__ Cf32, int ldc, int K) {
    constexpr int BM = 2 * WM, BN = 2 * WN, MI = WM / 16, NI = WN / 16;
    __shared__ uint4 As[BM * 8];
    __shared__ uint4 Bs[BN * 8];

    const int t = threadIdx.x;
    const int lane = t & 63, w = t >> 6;
    const int wr = w >> 1, wc = w & 1;
    const int row0 = blockIdx.y * BM, col0 = blockIdx.x * BN;
    const int l15 = lane & 15, l4 = lane >> 4;

    f32x4 acc[MI][NI];
    #pragma unroll
    for (int mi = 0; mi < MI; ++mi)
        #pragma unroll
        for (int ni = 0; ni < NI; ++ni) acc[mi][ni] = (f32x4){0.f, 0.f, 0.f, 0.f};

    for (int k0 = 0; k0 < K; k0 += 64) {
        #pragma unroll
        for (int j = 0; j < BM / 32; ++j) {
            const int ci = t + 256 * j, r = ci >> 3, c = ci & 7;
            As[r * 8 + (c ^ (r & 7))] =
                *reinterpret_cast<const uint4*>(&A[(size_t)(row0 + r) * lda + k0 + c * 8]);
        }
        #pragma unroll
        for (int j = 0; j < BN / 32; ++j) {
            const int ci = t + 256 * j, r = ci >> 3, c = ci & 7;
            Bs[r * 8 + (c ^ (r & 7))] =
                *reinterpret_cast<const uint4*>(&Wt[(size_t)(col0 + r) * K + k0 + c * 8]);
        }
        __syncthreads();

        #pragma unroll
        for (int tk = 0; tk < 2; ++tk) {
            f16x8 af[MI], bf[NI];
            #pragma unroll
            for (int mi = 0; mi < MI; ++mi) {
                const int r = wr * WM + mi * 16 + l15;
                af[mi] = *reinterpret_cast<const f16x8*>(&As[r * 8 + ((tk * 4 + l4) ^ (r & 7))]);
            }
            #pragma unroll
            for (int ni = 0; ni < NI; ++ni) {
                const int r = wc * WN + ni * 16 + l15;
                bf[ni] = *reinterpret_cast<const f16x8*>(&Bs[r * 8 + ((tk * 4 + l4) ^ (r & 7))]);
            }
            #pragma unroll
            for (int mi = 0; mi < MI; ++mi)
                #pragma unroll
                for (int ni = 0; ni < NI; ++ni)
                    acc[mi][ni] = __builtin_amdgcn_mfma_f32_16x16x32_f16(
                        af[mi], bf[ni], acc[mi][ni], 0, 0, 0);
        }
        __syncthreads();
    }

    #pragma unroll
    for (int mi = 0; mi < MI; ++mi) {
        #pragma unroll
        for (int ni = 0; ni < NI; ++ni) {
            const int col = col0 + wc * WN + ni * 16 + l15;
            float bv = 0.f;
            if constexpr (BIAS) bv = bias[col];
            #pragma unroll
            for (int r = 0; r < 4; ++r) {
                const size_t row = row0 + wr * WM + mi * 16 + l4 * 4 + r;
                float v = acc[mi][ni][r] + bv;
                if constexpr (GELU) v = gelu_f(v);
                if constexpr (OUTF16) {
                    Cf16[row * ldc + col] = (f16)v;
                } else {
                    float* p = &Cf32[row * ldc + col];
                    *p = RES ? (*p + v) : v;
                }
            }
        }
    }
}

// ---------------------------------------------------------------------------
// Flash attention, f16 MFMA, in-place (writes Q slot of qkv).
// 512 threads = 8 waves; wave w owns q rows [w*16, w*16+16); QBLK=128, KT=64.
// K/V double-buffered in LDS (one barrier per kt); next-tile global loads
// issued into registers under the current tile's compute (T14).
// grid (N/128, CB*H).
// ---------------------------------------------------------------------------
__global__ __launch_bounds__(512, 2)
void attn_f16(f16* __restrict__ qkv, const f16* __restrict__ Vt) {
    // 144KB carve: K dbuf 2x32KB | V dbuf 2x32KB | P 16KB
    __shared__ uint4 lds[9216];
    f16* Ps = (f16*)(lds + 8192);            // [128 x 64] f16, XOR-swizzled

    const int t = threadIdx.x, lane = t & 63, w = t >> 6;
    const int l15 = lane & 15, l4 = lane >> 4;
    const int bh = blockIdx.y;
    const int b = bh >> 3, hh = bh & 7;
    const int q0 = blockIdx.x * 128;

    f16* Qg = qkv + (size_t)b * N_ * QS_ + hh * 256;
    const f16* Kg = Qg + 2048;
    const f16* Vtg = Vt + ((size_t)b * INNER_ + hh * 256) * N_;

    // ---- stage Q (128x256 f16 = 4096 chunks) through lds[0..4095]
    uint4 qreg[8];
    #pragma unroll
    for (int j = 0; j < 8; ++j) {
        const int ci = t + 512 * j, r = ci >> 5, c = ci & 31;
        qreg[j] = *reinterpret_cast<const uint4*>(&Qg[(size_t)(q0 + r) * QS_ + c * 8]);
    }
    // kt=0 K/V loads issued early (land while Q staging completes)
    uint4 kreg[4], vreg[4];
    #pragma unroll
    for (int j = 0; j < 4; ++j) {
        const int ci = t + 512 * j, r = ci >> 5, c = ci & 31;
        kreg[j] = *reinterpret_cast<const uint4*>(&Kg[(size_t)r * QS_ + c * 8]);
    }
    #pragma unroll
    for (int j = 0; j < 4; ++j) {
        const int ci = t + 512 * j, r = ci >> 3, c = ci & 7;
        vreg[j] = *reinterpret_cast<const uint4*>(&Vtg[(size_t)r * N_ + c * 8]);
    }
    #pragma unroll
    for (int j = 0; j < 8; ++j) {
        const int ci = t + 512 * j, r = ci >> 5, c = ci & 31;
        lds[r * 32 + (c ^ (r & 7))] = qreg[j];
    }
    __syncthreads();
    f16x8 qf[8];
    {
        const int r = w * 16 + l15;
        #pragma unroll
        for (int tk = 0; tk < 8; ++tk)
            qf[tk] = *reinterpret_cast<const f16x8*>(&lds[r * 32 + ((tk * 4 + l4) ^ (r & 7))]);
    }
    __syncthreads();   // Q frags in regs before K staging overwrites lds[0..2047]

    float m_run[4] = {-INFINITY, -INFINITY, -INFINITY, -INFINITY};
    float l_run[4] = {0.f, 0.f, 0.f, 0.f};
    f32x4 outf[16];
    #pragma unroll
    for (int f = 0; f < 16; ++f) outf[f] = (f32x4){0.f, 0.f, 0.f, 0.f};

    for (int kt = 0; kt < 16; ++kt) {
        uint4* Kc = (kt & 1) ? (lds + 2048) : lds;
        uint4* Vc = (kt & 1) ? (lds + 6144) : (lds + 4096);

        // commit staged regs for this tile
        #pragma unroll
        for (int j = 0; j < 4; ++j) {
            const int ci = t + 512 * j, r = ci >> 5, c = ci & 31;
            Kc[r * 32 + (c ^ (r & 7))] = kreg[j];
        }
        #pragma unroll
        for (int j = 0; j < 4; ++j) {
            const int ci = t + 512 * j, r = ci >> 3, c = ci & 7;
            Vc[r * 8 + (c ^ (r & 7))] = vreg[j];
        }
        // issue next tile's loads (hidden under this tile's compute)
        if (kt < 15) {
            const int kv0n = (kt + 1) * 64;
            #pragma unroll
            for (int j = 0; j < 4; ++j) {
                const int ci = t + 512 * j, r = ci >> 5, c = ci & 31;
                kreg[j] = *reinterpret_cast<const uint4*>(
                    &Kg[(size_t)(kv0n + r) * QS_ + c * 8]);
            }
            #pragma unroll
            for (int j = 0; j < 4; ++j) {
                const int ci = t + 512 * j, r = ci >> 3, c = ci & 7;
                vreg[j] = *reinterpret_cast<const uint4*>(
                    &Vtg[(size_t)r * N_ + kv0n + c * 8]);
            }
        }
        __syncthreads();   // single barrier per kt: staging of kt visible

        // S = Q @ K^T  (wave: 16 q x 64 kv)
        f32x4 sf[4];
        #pragma unroll
        for (int nf = 0; nf < 4; ++nf) sf[nf] = (f32x4){0.f, 0.f, 0.f, 0.f};
        #pragma unroll
        for (int tk = 0; tk < 8; ++tk) {
            #pragma unroll
            for (int nf = 0; nf < 4; ++nf) {
                const int r = nf * 16 + l15;
                const f16x8 bf =
                    *reinterpret_cast<const f16x8*>(&Kc[r * 32 + ((tk * 4 + l4) ^ (r & 7))]);
                sf[nf] = __builtin_amdgcn_mfma_f32_16x16x32_f16(qf[tk], bf, sf[nf], 0, 0, 0);
            }
        }

        // online softmax over kv (rows: q = w*16 + 4*l4 + r)
        float mx[4], al[4], ps[4], p[4][4];
        #pragma unroll
        for (int r = 0; r < 4; ++r) {
            float v0 = sf[0][r] * SCALE_, v1 = sf[1][r] * SCALE_;
            float v2 = sf[2][r] * SCALE_, v3 = sf[3][r] * SCALE_;
            p[0][r] = v0; p[1][r] = v1; p[2][r] = v2; p[3][r] = v3;
            mx[r] = fmaxf(fmaxf(v0, v1), fmaxf(v2, v3));
        }
        #pragma unroll
        for (int off = 1; off < 16; off <<= 1)
            #pragma unroll
            for (int r = 0; r < 4; ++r) mx[r] = fmaxf(mx[r], __shfl_xor(mx[r], off));
        #pragma unroll
        for (int r = 0; r < 4; ++r) {
            const float nm = fmaxf(m_run[r], mx[r]);
            al[r] = __expf(m_run[r] - nm);
            m_run[r] = nm;
            float sum = 0.f;
            #pragma unroll
            for (int nf = 0; nf < 4; ++nf) {
                p[nf][r] = __expf(p[nf][r] - nm);
                sum += p[nf][r];
            }
            ps[r] = sum;
        }
        #pragma unroll
        for (int off = 1; off < 16; off <<= 1)
            #pragma unroll
            for (int r = 0; r < 4; ++r) ps[r] += __shfl_xor(ps[r], off);
        // P is wave-private (write rows == read rows) -> no barrier needed
        #pragma unroll
        for (int r = 0; r < 4; ++r) {
            l_run[r] = l_run[r] * al[r] + ps[r];
            const int q = w * 16 + l4 * 4 + r;
            #pragma unroll
            for (int nf = 0; nf < 4; ++nf) {
                const int kv = nf * 16 + l15;
                Ps[q * 64 + (kv ^ ((q & 7) << 3))] = (f16)p[nf][r];
            }
        }
        #pragma unroll
        for (int f = 0; f < 16; ++f)
            #pragma unroll
            for (int r = 0; r < 4; ++r) outf[f][r] *= al[r];

        // PV: out += P @ V   (B-frags from Vt rows, kv-contiguous)
        #pragma unroll
        for (int tk = 0; tk < 2; ++tk) {
            const int rq = w * 16 + l15;
            const int c = tk * 4 + l4;
            const f16x8 pa =
                *reinterpret_cast<const f16x8*>(&Ps[rq * 64 + ((c ^ (rq & 7)) * 8)]);
            #pragma unroll
            for (int f = 0; f < 16; ++f) {
                const int d = f * 16 + l15;
                const f16x8 vf = *reinterpret_cast<const f16x8*>(&Vc[d * 8 + (c ^ (d & 7))]);
                outf[f] = __builtin_amdgcn_mfma_f32_16x16x32_f16(pa, vf, outf[f], 0, 0, 0);
            }
        }
        // no trailing barrier: next iteration writes the other LDS buffer
    }

    // normalize, write back to Q slot
    float inv[4];
    #pragma unroll
    for (int r = 0; r < 4; ++r) inv[r] = 1.0f / l_run[r];
    #pragma unroll
    for (int f = 0; f < 16; ++f) {
        const int d = f * 16 + l15;
        #pragma unroll
        for (int r = 0; r < 4; ++r) {
            const int q = w * 16 + l4 * 4 + r;
            Qg[(size_t)(q0 + q) * QS_ + d] = (f16)(outf[f][r] * inv[r]);
        }
    }
}

// ---------------------------------------------------------------------------
extern "C" void kernel_launch(void* const* d_in, const int* in_sizes, int n_in,
                              void* d_out, int out_size, void* d_ws, size_t ws_size,
                              hipStream_t stream) {
    (void)in_sizes; (void)n_in; (void)out_size;

    const float* inputs = (const float*)d_in[0];
    const float* ln1_g  = (const float*)d_in[1];
    const float* ln1_b  = (const float*)d_in[2];
    const float* w_qkv  = (const float*)d_in[3];
    const float* w_proj = (const float*)d_in[4];
    const float* b_proj = (const float*)d_in[5];
    const float* ln2_g  = (const float*)d_in[6];
    const float* ln2_b  = (const float*)d_in[7];
    const float* w1     = (const float*)d_in[8];
    const float* b1     = (const float*)d_in[9];
    const float* w2     = (const float*)d_in[10];
    const float* b2     = (const float*)d_in[11];

    float* x = (float*)d_out;               // running residual [R x D] fp32

    // ws carve-up (all f16)
    f16* ws = (f16*)d_ws;
    const size_t SZ_WQKV = (size_t)L_ * D_ * 3 * INNER_;   // 6.29M
    const size_t SZ_WPRJ = (size_t)L_ * INNER_ * D_;       // 2.10M
    const size_t SZ_W1   = (size_t)L_ * D_ * M_;           // 1.05M
    const size_t SZ_W2   = (size_t)L_ * M_ * D_;           // 1.05M
    const size_t SZ_H    = (size_t)R_ * D_;                // 2.10M
    f16* wt_qkv = ws;
    f16* wt_prj = wt_qkv + SZ_WQKV;
    f16* wt1    = wt_prj + SZ_WPRJ;
    f16* wt2    = wt1 + SZ_W1;
    f16* h      = wt2 + SZ_W2;
    f16* qc     = h + SZ_H;                 // per-chunk qkv [CR x 6144]

    const size_t fixed = SZ_WQKV + SZ_WPRJ + SZ_W1 + SZ_W2 + SZ_H;
    int nch = 1;
    while (nch < 8 &&
           2 * (fixed + ((size_t)R_ / nch) * (QS_ + INNER_)) > ws_size)
        nch *= 2;
    const int CB = B_ / nch;
    const int CR = R_ / nch;
    f16* vt = qc + (size_t)CR * QS_;        // per-chunk Vt [CB x 2048 x 1024]

    hipMemcpyAsync(x, inputs, (size_t)R_ * D_ * sizeof(float),
                   hipMemcpyDeviceToDevice, stream);

    // weight prep (every call; deterministic)
    transpose_w<<<dim3(96, 4, L_), 256, 0, stream>>>(w_qkv, wt_qkv, D_, 3 * INNER_);
    transpose_w<<<dim3(4, 32, L_), 256, 0, stream>>>(w_proj, wt_prj, INNER_, D_);
    transpose_w<<<dim3(16, 4, L_), 256, 0, stream>>>(w1, wt1, D_, M_);
    transpose_w<<<dim3(4, 16, L_), 256, 0, stream>>>(w2, wt2, M_, D_);

    for (int l = 0; l < L_; ++l) {
        ln_kernel<<<R_, 256, 0, stream>>>(x, ln1_g + l * D_, ln1_b + l * D_, h);

        for (int c = 0; c < nch; ++c) {
            const size_t r0 = (size_t)c * CR;
            gemm_f16<64, 64, false, false, false, true>
                <<<dim3(QS_ / 128, CR / 128), 256, 0, stream>>>(
                    h + r0 * D_, D_, wt_qkv + (size_t)l * D_ * 3 * INNER_,
                    nullptr, qc, nullptr, QS_, D_);

            transpose_v<<<dim3(16, 32, CB), 256, 0, stream>>>(qc, vt);

            attn_f16<<<dim3(N_ / 128, CB * H_), 512, 0, stream>>>(qc, vt);

            gemm_f16<32, 32, true, true, false, false>
                <<<dim3(D_ / 64, CR / 64), 256, 0, stream>>>(
                    qc, QS_, wt_prj + (size_t)l * INNER_ * D_,
                    b_proj + l * D_, nullptr, x + r0 * D_, D_, INNER_);
        }

        ln_kernel<<<R_, 256, 0, stream>>>(x, ln2_g + l * D_, ln2_b + l * D_, h);

        for (int c = 0; c < nch; ++c) {
            const size_t r0 = (size_t)c * CR;
            f16* hid = qc;  // [CR x M] aliases qkv chunk buffer
            gemm_f16<64, 64, true, false, true, true>
                <<<dim3(M_ / 128, CR / 128), 256, 0, stream>>>(
                    h + r0 * D_, D_, wt1 + (size_t)l * D_ * M_,
                    b1 + l * M_, hid, nullptr, M_, D_);

            gemm_f16<32, 32, true, true, false, false>
                <<<dim3(D_ / 64, CR / 64), 256, 0, stream>>>(
                    hid, M_, wt2 + (size_t)l * M_ * D_,
                    b2 + l * D_, nullptr, x + r0 * D_, D_, M_);
        }
    }
}